// Round 4
// baseline (738.398 us; speedup 1.0000x reference)
//
#include <hip/hip_runtime.h>
#include <hip/hip_bf16.h>

#define DIM 64
#define NREL 8
#define KS 512              // Sx width: 8 relation blocks (root handled from xb)
#define KTOT 576            // GEMM K: 512 + 64 root
#define WT_STRIDE 584       // padded LDS row stride (bf16), 292 dwords -> 2-way max

typedef __bf16 bf16x8 __attribute__((ext_vector_type(8)));
typedef float  f32x4  __attribute__((ext_vector_type(4)));

// ---------------- histogram over (dst, rel) ----------------
__global__ __launch_bounds__(256) void hist_kernel(const int* __restrict__ dst,
                                                   const int* __restrict__ et,
                                                   int* __restrict__ deg8, int E) {
    int i = blockIdx.x * 256 + threadIdx.x;
    if (i < E) atomicAdd(&deg8[dst[i] * 8 + et[i]], 1);
}

// ---------------- per-dst totals + inv_deg ----------------
__global__ __launch_bounds__(256) void sum8_kernel(const int* __restrict__ deg8,
                                                   int* __restrict__ degi,
                                                   float* __restrict__ invdeg, int N) {
    int d = blockIdx.x * 256 + threadIdx.x;
    if (d >= N) return;
    int s = 0;
#pragma unroll
    for (int r = 0; r < NREL; ++r) s += deg8[d * 8 + r];
    degi[d] = s;
    invdeg[d] = 1.0f / fmaxf((float)s, 1.0f);
}

// ---------------- 3-kernel exclusive scan over degi ----------------
__global__ __launch_bounds__(256) void scan1_kernel(const int* __restrict__ degi,
                                                    int* __restrict__ offs,
                                                    int* __restrict__ bsum, int N) {
    __shared__ int sd[256];
    int tid = threadIdx.x;
    int i = blockIdx.x * 256 + tid;
    int v = (i < N) ? degi[i] : 0;
    sd[tid] = v;
    __syncthreads();
#pragma unroll
    for (int off = 1; off < 256; off <<= 1) {
        int t = (tid >= off) ? sd[tid - off] : 0;
        __syncthreads();
        sd[tid] += t;
        __syncthreads();
    }
    if (i < N) offs[i] = sd[tid] - v;
    if (tid == 255) bsum[blockIdx.x] = sd[255];
}

__global__ __launch_bounds__(512) void scan2_kernel(int* __restrict__ bsum, int nb) {
    __shared__ int sd[512];
    int tid = threadIdx.x;
    int v = (tid < nb) ? bsum[tid] : 0;
    sd[tid] = v;
    __syncthreads();
#pragma unroll
    for (int off = 1; off < 512; off <<= 1) {
        int t = (tid >= off) ? sd[tid - off] : 0;
        __syncthreads();
        sd[tid] += t;
        __syncthreads();
    }
    if (tid < nb) bsum[tid] = sd[tid] - v;
}

__global__ __launch_bounds__(256) void scan3_kernel(int* __restrict__ offs,
                                                    const int* __restrict__ bsum, int N) {
    int i = blockIdx.x * 256 + threadIdx.x;
    if (i < N) offs[i] += bsum[blockIdx.x];
}

// ---------------- rp[d*8+r] = offs[d] + prefix(deg8[d][0..r]) ----------------
__global__ __launch_bounds__(256) void rpbuild_kernel(const int* __restrict__ deg8,
                                                      const int* __restrict__ offs,
                                                      int* __restrict__ rp, int N, int E) {
    int d = blockIdx.x * 256 + threadIdx.x;
    if (d >= N) return;
    int base = offs[d];
    int run = 0;
#pragma unroll
    for (int r = 0; r < NREL; ++r) {
        rp[d * 8 + r] = base + run;
        run += deg8[d * 8 + r];
    }
    if (d == 0) rp[(size_t)N * 8] = E;
}

// ---------------- bucket: srcs sorted by (dst, rel) ----------------
__global__ __launch_bounds__(256) void bucket_kernel(const int* __restrict__ src,
                                                     const int* __restrict__ dst,
                                                     const int* __restrict__ et,
                                                     const int* __restrict__ rp,
                                                     int* __restrict__ cursor8,
                                                     int* __restrict__ srcs, int E) {
    int i = blockIdx.x * 256 + threadIdx.x;
    if (i >= E) return;
    int cell = dst[i] * 8 + et[i];
    int p = rp[cell] + atomicAdd(&cursor8[cell], 1);
    srcs[p] = src[i];
}

// ---------------- initial gather: xb = bf16(node_emb[x_idx]) ----------------
__global__ __launch_bounds__(256) void gather_kernel(const int* __restrict__ x_idx,
                                                     const float* __restrict__ emb,
                                                     __bf16* __restrict__ xb, int N) {
    int i = blockIdx.x * 256 + threadIdx.x;
    if (i >= N * DIM) return;
    int n = i >> 6;
    int c = i & 63;
    xb[i] = (__bf16)emb[(size_t)x_idx[n] * DIM + c];
}

// ---------------- aggregate: one wave per (dst, rel) cell; 4-wide clamped unroll
__global__ __launch_bounds__(1024) void aggregate_kernel(const __bf16* __restrict__ xb,
                                                         const int* __restrict__ srcs,
                                                         const int* __restrict__ rp,
                                                         const float* __restrict__ invdeg,
                                                         __bf16* __restrict__ Sx, int ncells) {
    int wid = blockIdx.x * 16 + (threadIdx.x >> 6);
    int cell = __builtin_amdgcn_readfirstlane(wid);   // wave-uniform -> scalar loads
    if (cell >= ncells) return;
    int lane = threadIdx.x & 63;
    int d = cell >> 3;
    int b0 = rp[cell];
    int b1 = rp[cell + 1];
    float acc = 0.f;
    for (int j = b0; j < b1; j += 4) {
        int j1 = min(j + 1, b1 - 1);
        int j2 = min(j + 2, b1 - 1);
        int j3 = min(j + 3, b1 - 1);
        int s0 = srcs[j];                 // scalar loads (uniform addr)
        int s1 = srcs[j1];
        int s2 = srcs[j2];
        int s3 = srcs[j3];
        float v0 = (float)xb[(size_t)s0 * DIM + lane];   // 4 independent gathers in flight
        float v1 = (float)xb[(size_t)s1 * DIM + lane];
        float v2 = (float)xb[(size_t)s2 * DIM + lane];
        float v3 = (float)xb[(size_t)s3 * DIM + lane];
        acc += v0;
        if (j + 1 < b1) acc += v1;        // uniform predicates
        if (j + 2 < b1) acc += v2;
        if (j + 3 < b1) acc += v3;
    }
    Sx[(size_t)d * KS + ((cell & 7) << 6) + lane] = (__bf16)(acc * invdeg[d]);
}

// ---------------- GEMM: xout = relu([Sx | xb] @ Wcat[576,64] + bias), bf16 MFMA
// Wcat rows 0..511: weight[r][i][o] at k = r*64+i; rows 512..575: root[i][o].
__global__ __launch_bounds__(256) void gemm_kernel(const __bf16* __restrict__ Sx,
                                                   const __bf16* __restrict__ xin,
                                                   const float* __restrict__ weight_l, // [8,64,64]
                                                   const float* __restrict__ root_l,   // [64,64]
                                                   const float* __restrict__ bias_l,   // [64]
                                                   __bf16* __restrict__ xout, int N) {
    __shared__ __bf16 Wt[64 * WT_STRIDE];

    for (int idx = threadIdx.x; idx < KTOT * 64; idx += 256) {
        int k = idx >> 6;
        int c = idx & 63;
        float w = (k < KS) ? weight_l[((k >> 6) << 12) + ((k & 63) << 6) + c]
                           : root_l[((k - KS) << 6) + c];
        Wt[c * WT_STRIDE + k] = (__bf16)w;
    }
    __syncthreads();

    int wave = threadIdx.x >> 6;
    int lane = threadIdx.x & 63;
    int l15 = lane & 15;
    int lg  = lane >> 4;
    int ntiles = (N + 63) >> 6;

    for (int tile = blockIdx.x; tile < ntiles; tile += gridDim.x) {
        int n0 = tile * 64;
        int row_a = n0 + 16 * wave + l15;
        if (row_a >= N) row_a = N - 1;
        const __bf16* arow = Sx  + (size_t)row_a * KS  + lg * 8;
        const __bf16* xrow = xin + (size_t)row_a * DIM + lg * 8;

        f32x4 acc[4];
#pragma unroll
        for (int t = 0; t < 4; ++t) acc[t] = (f32x4){0.f, 0.f, 0.f, 0.f};

#pragma unroll
        for (int kk = 0; kk < KTOT / 32; ++kk) {
            int k0 = kk * 32;
            bf16x8 av = (k0 < KS)
                ? *reinterpret_cast<const bf16x8*>(arow + k0)
                : *reinterpret_cast<const bf16x8*>(xrow + (k0 - KS));
#pragma unroll
            for (int t = 0; t < 4; ++t) {
                bf16x8 bv = *reinterpret_cast<const bf16x8*>(
                    &Wt[(16 * t + l15) * WT_STRIDE + k0 + lg * 8]);
                acc[t] = __builtin_amdgcn_mfma_f32_16x16x32_bf16(av, bv, acc[t], 0, 0, 0);
            }
        }

#pragma unroll
        for (int t = 0; t < 4; ++t) {
            int c = 16 * t + l15;
            float b = bias_l[c];
#pragma unroll
            for (int i = 0; i < 4; ++i) {
                int n = n0 + 16 * wave + 4 * lg + i;
                if (n < N) {
                    float v = acc[t][i] + b;
                    xout[(size_t)n * DIM + c] = (__bf16)fmaxf(v, 0.f);
                }
            }
        }
    }
}

// ---------------- score ----------------
__global__ __launch_bounds__(256) void score_kernel(const __bf16* __restrict__ xb,
                                                    const int* __restrict__ s,
                                                    const int* __restrict__ t,
                                                    float* __restrict__ out, int T) {
    int i = blockIdx.x * 4 + (threadIdx.x >> 6);
    if (i >= T) return;
    int lane = threadIdx.x & 63;
    float p = (float)xb[(size_t)s[i] * DIM + lane] * (float)xb[(size_t)t[i] * DIM + lane];
#pragma unroll
    for (int off = 32; off > 0; off >>= 1) p += __shfl_down(p, off, 64);
    if (lane == 0) out[i] = p;
}

extern "C" void kernel_launch(void* const* d_in, const int* in_sizes, int n_in,
                              void* d_out, int out_size, void* d_ws, size_t ws_size,
                              hipStream_t stream) {
    const int*   x_idx  = (const int*)d_in[0];
    const int*   eidx   = (const int*)d_in[1];   // [2,E]
    const int*   etyp   = (const int*)d_in[2];   // [E]
    const int*   tidx   = (const int*)d_in[3];   // [2,T]
    const float* emb    = (const float*)d_in[4]; // [N,64]
    const float* weight = (const float*)d_in[5]; // [L,8,64,64]
    const float* root   = (const float*)d_in[6]; // [L,64,64]
    const float* bias   = (const float*)d_in[7]; // [L,64]

    int N = in_sizes[0];
    int E = in_sizes[2];
    int T = in_sizes[3] / 2;
    int L = in_sizes[5] / (NREL * DIM * DIM);

    const int* src = eidx;
    const int* dst = eidx + E;
    const int* ts  = tidx;
    const int* tt  = tidx + T;
    float* out = (float*)d_out;

    // ---- workspace carve-up ----
    char* p = (char*)d_ws;
    auto alloc = [&](size_t bytes) -> void* {
        void* r = (void*)p;
        p += (bytes + 255) & ~(size_t)255;
        return r;
    };
    __bf16* Sx     = (__bf16*)alloc((size_t)N * KS * sizeof(__bf16));
    __bf16* xb     = (__bf16*)alloc((size_t)N * DIM * sizeof(__bf16));
    int*    srcs   = (int*)   alloc((size_t)E * sizeof(int));
    int*    deg8   = (int*)   alloc((size_t)N * 8 * sizeof(int));   // reused as cursor8
    int*    rp     = (int*)   alloc(((size_t)N * 8 + 1) * sizeof(int));
    int*    degi   = (int*)   alloc((size_t)N * sizeof(int));
    int*    offs   = (int*)   alloc((size_t)N * sizeof(int));
    float*  invdeg = (float*) alloc((size_t)N * sizeof(float));
    int*    bsum   = (int*)   alloc(1024 * sizeof(int));

    int nb = (N + 255) / 256;

    hipMemsetAsync(deg8, 0, (size_t)N * 8 * sizeof(int), stream);
    hist_kernel<<<(E + 255) / 256, 256, 0, stream>>>(dst, etyp, deg8, E);
    sum8_kernel<<<nb, 256, 0, stream>>>(deg8, degi, invdeg, N);
    scan1_kernel<<<nb, 256, 0, stream>>>(degi, offs, bsum, N);
    scan2_kernel<<<1, 512, 0, stream>>>(bsum, nb);
    scan3_kernel<<<nb, 256, 0, stream>>>(offs, bsum, N);
    rpbuild_kernel<<<nb, 256, 0, stream>>>(deg8, offs, rp, N, E);
    // deg8 no longer needed -> reuse as cursor8
    hipMemsetAsync(deg8, 0, (size_t)N * 8 * sizeof(int), stream);
    bucket_kernel<<<(E + 255) / 256, 256, 0, stream>>>(src, dst, etyp, rp, deg8, srcs, E);

    gather_kernel<<<((size_t)N * DIM + 255) / 256, 256, 0, stream>>>(x_idx, emb, xb, N);

    int ncells = N * NREL;
    int aggblocks = (ncells + 15) / 16;   // 16 waves per 1024-thread block
    for (int l = 0; l < L; ++l) {
        aggregate_kernel<<<aggblocks, 1024, 0, stream>>>(xb, srcs, rp, invdeg, Sx, ncells);
        gemm_kernel<<<512, 256, 0, stream>>>(Sx, xb,
                                             weight + (size_t)l * NREL * DIM * DIM,
                                             root + (size_t)l * DIM * DIM,
                                             bias + (size_t)l * DIM,
                                             xb, N);
    }

    score_kernel<<<(T + 3) / 4, 256, 0, stream>>>(xb, ts, tt, out, T);
}

// Round 5
// 546.805 us; speedup vs baseline: 1.3504x; 1.3504x over previous
//
#include <hip/hip_runtime.h>
#include <hip/hip_bf16.h>

#define DIM 64
#define NREL 8
#define KS 512              // Sx width: 8 relation blocks (root handled from xb)
#define KTOT 576            // GEMM K: 512 + 64 root

typedef __bf16 bf16x8 __attribute__((ext_vector_type(8)));
typedef float  f32x4  __attribute__((ext_vector_type(4)));

// ---------------- histogram over (dst, rel) ----------------
__global__ __launch_bounds__(256) void hist_kernel(const int* __restrict__ dst,
                                                   const int* __restrict__ et,
                                                   int* __restrict__ deg8, int E) {
    int i = blockIdx.x * 256 + threadIdx.x;
    if (i < E) atomicAdd(&deg8[dst[i] * 8 + et[i]], 1);
}

// ---------------- per-dst totals + inv_deg ----------------
__global__ __launch_bounds__(256) void sum8_kernel(const int* __restrict__ deg8,
                                                   int* __restrict__ degi,
                                                   float* __restrict__ invdeg, int N) {
    int d = blockIdx.x * 256 + threadIdx.x;
    if (d >= N) return;
    int s = 0;
#pragma unroll
    for (int r = 0; r < NREL; ++r) s += deg8[d * 8 + r];
    degi[d] = s;
    invdeg[d] = 1.0f / fmaxf((float)s, 1.0f);
}

// ---------------- 3-kernel exclusive scan over degi ----------------
__global__ __launch_bounds__(256) void scan1_kernel(const int* __restrict__ degi,
                                                    int* __restrict__ offs,
                                                    int* __restrict__ bsum, int N) {
    __shared__ int sd[256];
    int tid = threadIdx.x;
    int i = blockIdx.x * 256 + tid;
    int v = (i < N) ? degi[i] : 0;
    sd[tid] = v;
    __syncthreads();
#pragma unroll
    for (int off = 1; off < 256; off <<= 1) {
        int t = (tid >= off) ? sd[tid - off] : 0;
        __syncthreads();
        sd[tid] += t;
        __syncthreads();
    }
    if (i < N) offs[i] = sd[tid] - v;
    if (tid == 255) bsum[blockIdx.x] = sd[255];
}

__global__ __launch_bounds__(512) void scan2_kernel(int* __restrict__ bsum, int nb) {
    __shared__ int sd[512];
    int tid = threadIdx.x;
    int v = (tid < nb) ? bsum[tid] : 0;
    sd[tid] = v;
    __syncthreads();
#pragma unroll
    for (int off = 1; off < 512; off <<= 1) {
        int t = (tid >= off) ? sd[tid - off] : 0;
        __syncthreads();
        sd[tid] += t;
        __syncthreads();
    }
    if (tid < nb) bsum[tid] = sd[tid] - v;
}

__global__ __launch_bounds__(256) void scan3_kernel(int* __restrict__ offs,
                                                    const int* __restrict__ bsum, int N) {
    int i = blockIdx.x * 256 + threadIdx.x;
    if (i < N) offs[i] += bsum[blockIdx.x];
}

// ---------------- rp[d*8+r] = offs[d] + prefix(deg8[d][0..r]) ----------------
__global__ __launch_bounds__(256) void rpbuild_kernel(const int* __restrict__ deg8,
                                                      const int* __restrict__ offs,
                                                      int* __restrict__ rp, int N, int E) {
    int d = blockIdx.x * 256 + threadIdx.x;
    if (d >= N) return;
    int base = offs[d];
    int run = 0;
#pragma unroll
    for (int r = 0; r < NREL; ++r) {
        rp[d * 8 + r] = base + run;
        run += deg8[d * 8 + r];
    }
    if (d == 0) rp[(size_t)N * 8] = E;
}

// ---------------- bucket: srcs sorted by (dst, rel) ----------------
__global__ __launch_bounds__(256) void bucket_kernel(const int* __restrict__ src,
                                                     const int* __restrict__ dst,
                                                     const int* __restrict__ et,
                                                     const int* __restrict__ rp,
                                                     int* __restrict__ cursor8,
                                                     int* __restrict__ srcs, int E) {
    int i = blockIdx.x * 256 + threadIdx.x;
    if (i >= E) return;
    int cell = dst[i] * 8 + et[i];
    int p = rp[cell] + atomicAdd(&cursor8[cell], 1);
    srcs[p] = src[i];
}

// ---------------- initial gather: xb = bf16(node_emb[x_idx]) ----------------
__global__ __launch_bounds__(256) void gather_kernel(const int* __restrict__ x_idx,
                                                     const float* __restrict__ emb,
                                                     __bf16* __restrict__ xb, int N) {
    int i = blockIdx.x * 256 + threadIdx.x;
    if (i >= N * DIM) return;
    int n = i >> 6;
    int c = i & 63;
    xb[i] = (__bf16)emb[(size_t)x_idx[n] * DIM + c];
}

// ---------------- Wcat pre-convert: Wt[l][c][k] bf16, k in [0,576) ----------------
__global__ __launch_bounds__(256) void wcat_kernel(const float* __restrict__ weight, // [L,8,64,64]
                                                   const float* __restrict__ root,   // [L,64,64]
                                                   __bf16* __restrict__ Wt, int L) {
    int idx = blockIdx.x * 256 + threadIdx.x;
    int total = L * 64 * KTOT;
    if (idx >= total) return;
    int l = idx / (64 * KTOT);
    int rem = idx - l * 64 * KTOT;
    int c = rem / KTOT;
    int k = rem - c * KTOT;
    float w = (k < KS) ? weight[(((l * 8 + (k >> 6)) * 64) + (k & 63)) * 64 + c]
                       : root[(l * 64 + (k - KS)) * 64 + c];
    Wt[idx] = (__bf16)w;
}

// ---------------- aggregate: wave per dst; chunked vector load of srcs + readlane
__global__ __launch_bounds__(256) void aggregate_kernel(const __bf16* __restrict__ xb,
                                                        const int* __restrict__ srcs,
                                                        const int* __restrict__ rp,
                                                        const float* __restrict__ invdeg,
                                                        __bf16* __restrict__ Sx, int N, int E) {
    int d0 = blockIdx.x * 4 + (threadIdx.x >> 6);
    if (d0 >= N) return;
    int d = __builtin_amdgcn_readfirstlane(d0);
    int lane = threadIdx.x & 63;
    int rpv[9];
#pragma unroll
    for (int r = 0; r < 9; ++r) rpv[r] = rp[d * 8 + r];   // scalar loads (uniform)
    float inv = invdeg[d];
    __bf16* row = Sx + (size_t)d * KS;

    int j = rpv[0];
    int cbase = j;
    int u = (cbase + lane < E) ? srcs[cbase + lane] : 0;  // coalesced 64-wide chunk

#pragma unroll
    for (int r = 0; r < NREL; ++r) {
        int e = rpv[r + 1];
        float acc0 = 0.f, acc1 = 0.f;
        for (; j + 1 < e; j += 2) {
            if (j - cbase >= 64) { cbase += 64; u = (cbase + lane < E) ? srcs[cbase + lane] : 0; }
            int s0 = __builtin_amdgcn_readlane(u, j - cbase);
            if (j + 1 - cbase >= 64) { cbase += 64; u = (cbase + lane < E) ? srcs[cbase + lane] : 0; }
            int s1 = __builtin_amdgcn_readlane(u, j + 1 - cbase);
            float v0 = (float)xb[(size_t)s0 * DIM + lane];
            float v1 = (float)xb[(size_t)s1 * DIM + lane];
            acc0 += v0;
            acc1 += v1;
        }
        if (j < e) {
            if (j - cbase >= 64) { cbase += 64; u = (cbase + lane < E) ? srcs[cbase + lane] : 0; }
            int s0 = __builtin_amdgcn_readlane(u, j - cbase);
            acc0 += (float)xb[(size_t)s0 * DIM + lane];
            ++j;
        }
        row[(r << 6) + lane] = (__bf16)((acc0 + acc1) * inv);
    }
}

// ---------------- GEMM: xout = relu([Sx | xb] @ Wcat + bias), B-frags from global bf16 Wt
__global__ __launch_bounds__(256) void gemm_kernel(const __bf16* __restrict__ Sx,
                                                   const __bf16* __restrict__ xin,
                                                   const __bf16* __restrict__ Wt,    // [64][576] bf16
                                                   const float* __restrict__ bias_l, // [64]
                                                   __bf16* __restrict__ xout, int N) {
    int wave = threadIdx.x >> 6;
    int lane = threadIdx.x & 63;
    int l15 = lane & 15;
    int lg  = lane >> 4;

    int tile = blockIdx.x;
    int n0 = tile * 64;
    int row_a = n0 + 16 * wave + l15;
    if (row_a >= N) row_a = N - 1;
    const __bf16* arow = Sx  + (size_t)row_a * KS  + lg * 8;
    const __bf16* xrow = xin + (size_t)row_a * DIM + lg * 8;

    f32x4 acc[4];
#pragma unroll
    for (int t = 0; t < 4; ++t) acc[t] = (f32x4){0.f, 0.f, 0.f, 0.f};

#pragma unroll
    for (int kk = 0; kk < KTOT / 32; ++kk) {
        int k0 = kk * 32;
        bf16x8 av = (k0 < KS)
            ? *reinterpret_cast<const bf16x8*>(arow + k0)
            : *reinterpret_cast<const bf16x8*>(xrow + (k0 - KS));
#pragma unroll
        for (int t = 0; t < 4; ++t) {
            bf16x8 bv = *reinterpret_cast<const bf16x8*>(
                Wt + (size_t)(16 * t + l15) * KTOT + k0 + lg * 8);
            acc[t] = __builtin_amdgcn_mfma_f32_16x16x32_bf16(av, bv, acc[t], 0, 0, 0);
        }
    }

#pragma unroll
    for (int t = 0; t < 4; ++t) {
        int c = 16 * t + l15;
        float b = bias_l[c];
#pragma unroll
        for (int i = 0; i < 4; ++i) {
            int n = n0 + 16 * wave + 4 * lg + i;
            if (n < N) {
                float v = acc[t][i] + b;
                xout[(size_t)n * DIM + c] = (__bf16)fmaxf(v, 0.f);
            }
        }
    }
}

// ---------------- score ----------------
__global__ __launch_bounds__(256) void score_kernel(const __bf16* __restrict__ xb,
                                                    const int* __restrict__ s,
                                                    const int* __restrict__ t,
                                                    float* __restrict__ out, int T) {
    int i = blockIdx.x * 4 + (threadIdx.x >> 6);
    if (i >= T) return;
    int lane = threadIdx.x & 63;
    float p = (float)xb[(size_t)s[i] * DIM + lane] * (float)xb[(size_t)t[i] * DIM + lane];
#pragma unroll
    for (int off = 32; off > 0; off >>= 1) p += __shfl_down(p, off, 64);
    if (lane == 0) out[i] = p;
}

extern "C" void kernel_launch(void* const* d_in, const int* in_sizes, int n_in,
                              void* d_out, int out_size, void* d_ws, size_t ws_size,
                              hipStream_t stream) {
    const int*   x_idx  = (const int*)d_in[0];
    const int*   eidx   = (const int*)d_in[1];   // [2,E]
    const int*   etyp   = (const int*)d_in[2];   // [E]
    const int*   tidx   = (const int*)d_in[3];   // [2,T]
    const float* emb    = (const float*)d_in[4]; // [N,64]
    const float* weight = (const float*)d_in[5]; // [L,8,64,64]
    const float* root   = (const float*)d_in[6]; // [L,64,64]
    const float* bias   = (const float*)d_in[7]; // [L,64]

    int N = in_sizes[0];
    int E = in_sizes[2];
    int T = in_sizes[3] / 2;
    int L = in_sizes[5] / (NREL * DIM * DIM);

    const int* src = eidx;
    const int* dst = eidx + E;
    const int* ts  = tidx;
    const int* tt  = tidx + T;
    float* out = (float*)d_out;

    // ---- workspace carve-up ----
    char* p = (char*)d_ws;
    auto alloc = [&](size_t bytes) -> void* {
        void* r = (void*)p;
        p += (bytes + 255) & ~(size_t)255;
        return r;
    };
    __bf16* Sx     = (__bf16*)alloc((size_t)N * KS * sizeof(__bf16));
    __bf16* xb     = (__bf16*)alloc((size_t)N * DIM * sizeof(__bf16));
    __bf16* Wt     = (__bf16*)alloc((size_t)L * 64 * KTOT * sizeof(__bf16));
    int*    srcs   = (int*)   alloc(((size_t)E + 64) * sizeof(int));
    int*    deg8   = (int*)   alloc((size_t)N * 8 * sizeof(int));   // reused as cursor8
    int*    rp     = (int*)   alloc(((size_t)N * 8 + 1) * sizeof(int));
    int*    degi   = (int*)   alloc((size_t)N * sizeof(int));
    int*    offs   = (int*)   alloc((size_t)N * sizeof(int));
    float*  invdeg = (float*) alloc((size_t)N * sizeof(float));
    int*    bsum   = (int*)   alloc(1024 * sizeof(int));

    int nb = (N + 255) / 256;

    hipMemsetAsync(deg8, 0, (size_t)N * 8 * sizeof(int), stream);
    hist_kernel<<<(E + 255) / 256, 256, 0, stream>>>(dst, etyp, deg8, E);
    sum8_kernel<<<nb, 256, 0, stream>>>(deg8, degi, invdeg, N);
    scan1_kernel<<<nb, 256, 0, stream>>>(degi, offs, bsum, N);
    scan2_kernel<<<1, 512, 0, stream>>>(bsum, nb);
    scan3_kernel<<<nb, 256, 0, stream>>>(offs, bsum, N);
    rpbuild_kernel<<<nb, 256, 0, stream>>>(deg8, offs, rp, N, E);
    // deg8 no longer needed -> reuse as cursor8
    hipMemsetAsync(deg8, 0, (size_t)N * 8 * sizeof(int), stream);
    bucket_kernel<<<(E + 255) / 256, 256, 0, stream>>>(src, dst, etyp, rp, deg8, srcs, E);

    gather_kernel<<<((size_t)N * DIM + 255) / 256, 256, 0, stream>>>(x_idx, emb, xb, N);
    wcat_kernel<<<(L * 64 * KTOT + 255) / 256, 256, 0, stream>>>(weight, root, Wt, L);

    int ntiles = (N + 63) / 64;
    for (int l = 0; l < L; ++l) {
        aggregate_kernel<<<(N + 3) / 4, 256, 0, stream>>>(xb, srcs, rp, invdeg, Sx, N, E);
        gemm_kernel<<<ntiles, 256, 0, stream>>>(Sx, xb,
                                                Wt + (size_t)l * 64 * KTOT,
                                                bias + (size_t)l * DIM,
                                                xb, N);
    }

    score_kernel<<<(T + 3) / 4, 256, 0, stream>>>(xb, ts, tt, out, T);
}